// Round 1
// baseline (250.183 us; speedup 1.0000x reference)
//
#include <hip/hip_runtime.h>

#define DIN 128
#define DG 64

typedef __attribute__((ext_vector_type(8))) short short8;
typedef __attribute__((ext_vector_type(4))) float f32x4;

// ---- bf16 helpers (RNE) ----
static __device__ __forceinline__ unsigned short f2bf(float x) {
    unsigned u = __builtin_bit_cast(unsigned, x);
    u = (u + 0x7FFF + ((u >> 16) & 1)) >> 16;
    return (unsigned short)u;
}
static __device__ __forceinline__ float bf2f(unsigned short s) {
    return __builtin_bit_cast(float, (unsigned)s << 16);
}
// unpack bf16 pair packed in a u32 (lo = low 16 bits, hi = high 16 bits)
static __device__ __forceinline__ float bflo(unsigned u) {
    return __builtin_bit_cast(float, u << 16);
}
static __device__ __forceinline__ float bfhi(unsigned u) {
    return __builtin_bit_cast(float, u & 0xFFFF0000u);
}

// Packed per-column record, 512B:
//   lane l in [0,32): bytes [l*16, l*16+8)  = h1 dims 4l..4l+3 (bf16 x4)
//                     bytes [l*16+8,+16)    = zj dims 2l,2l+1   (f32 x2)
// One 16B gather per edge per lane in k_aggregate.

// ---------- K1: degree+slot capture, fused with W0|W1 -> Bt transpose ----------
__global__ void k_pre(const int* __restrict__ rows, int* __restrict__ deg,
                      int* __restrict__ slot, int E, int nDeg,
                      const float* __restrict__ W0, const float* __restrict__ W1,
                      unsigned short* __restrict__ Bt) {
    int b = blockIdx.x;
    if (b < nDeg) {
        int e = b * 256 + threadIdx.x;
        if (e < E) slot[e] = atomicAdd(&deg[rows[e]], 1);
    } else {
        int k = b - nDeg;  // 0..127
        int c = threadIdx.x;
        const float* W = (c < 128) ? W0 : W1;
        Bt[c * 128 + k] = f2bf(W[k * 128 + (c & 127)]);
    }
}

// ---------- K2 roles, fused into one kernel ----------
// y==0 : zj = feat @ Wp (f32, gate-critical) + gpart/fdotg dots
// y==1 : h0 (f32) + h1 (bf16) via 16x16x32 bf16 MFMA + a_self/a_neigh
// y==2 : full exclusive scan deg -> rowptr via decoupled lookback (x < nbs)
#define AS_LD 132
#define ALD 136
#define SMEM_BYTES 25088  // max(32*132*4 + 32*64*4, 64*136*2 + 1024)

static __device__ __forceinline__ void zj_body(
    const float* __restrict__ feat, const float* __restrict__ Wp,
    const float* __restrict__ Wg,
    char* __restrict__ pack, float* __restrict__ gpart, float* __restrict__ fdotg,
    int N, char* smem) {
    float* As = (float*)smem;
    float* Bs = (float*)(smem + 32 * AS_LD * 4);
    int tid = threadIdx.x;
    int tx = tid & 15, ty = tid >> 4;
    int m0 = blockIdx.x * 128;
    if (m0 >= N) return;
    float acc[8][4];
    #pragma unroll
    for (int r = 0; r < 8; ++r)
        #pragma unroll
        for (int c = 0; c < 4; ++c) acc[r][c] = 0.f;
    float gdot[8], fdot[8];
    #pragma unroll
    for (int r = 0; r < 8; ++r) { gdot[r] = 0.f; fdot[r] = 0.f; }
    for (int kc = 0; kc < 128; kc += 32) {
        for (int i = tid; i < 1024; i += 256) {
            int m = i >> 3, kq = (i & 7) << 2;
            int node = m0 + m;
            float4 f;
            if (node < N) f = *(const float4*)&feat[(size_t)node * 128 + kc + kq];
            else          f = make_float4(0.f, 0.f, 0.f, 0.f);
            As[(kq + 0) * AS_LD + m] = f.x;
            As[(kq + 1) * AS_LD + m] = f.y;
            As[(kq + 2) * AS_LD + m] = f.z;
            As[(kq + 3) * AS_LD + m] = f.w;
        }
        for (int i = tid; i < 512; i += 256) {
            int k = i >> 4, cq = (i & 15) << 2;
            *(float4*)&Bs[k * 64 + cq] = *(const float4*)&Wp[(size_t)(kc + k) * 64 + cq];
        }
        __syncthreads();
        #pragma unroll 8
        for (int kk = 0; kk < 32; ++kk) {
            const float* ar = &As[kk * AS_LD];
            float4 a0 = *(const float4*)(ar + 4 * tx);
            float4 a1 = *(const float4*)(ar + 64 + 4 * tx);
            float4 b0v = *(const float4*)&Bs[kk * 64 + 4 * ty];
            float a[8] = {a0.x, a0.y, a0.z, a0.w, a1.x, a1.y, a1.z, a1.w};
            #pragma unroll
            for (int r = 0; r < 8; ++r) {
                acc[r][0] += a[r] * b0v.x; acc[r][1] += a[r] * b0v.y;
                acc[r][2] += a[r] * b0v.z; acc[r][3] += a[r] * b0v.w;
            }
            float g1 = Wg[kc + kk];        // Wg[0:128]   -> gpart
            float g2 = Wg[192 + kc + kk];  // Wg[192:320] -> fdotg
            #pragma unroll
            for (int r = 0; r < 8; ++r) { gdot[r] += a[r] * g1; fdot[r] += a[r] * g2; }
        }
        __syncthreads();
    }
    #pragma unroll
    for (int r = 0; r < 8; ++r) {
        int node = m0 + ((r < 4) ? (4 * tx + r) : (64 + 4 * tx + (r - 4)));
        if (node >= N) continue;
        // zj dims 4ty..4ty+3 -> record lanes 2ty (dims 4ty,4ty+1) and 2ty+1
        char* rb = pack + (size_t)node * 512 + (size_t)ty * 32 + 8;
        *(float2*)(rb)      = make_float2(acc[r][0], acc[r][1]);
        *(float2*)(rb + 16) = make_float2(acc[r][2], acc[r][3]);
        if (ty == 0) { gpart[node] = gdot[r]; fdotg[node] = fdot[r]; }
    }
}

static __device__ __forceinline__ void mfma_body(
    const float* __restrict__ feat, const unsigned short* __restrict__ Bt,
    const float* __restrict__ b0, const float* __restrict__ b1,
    const float* __restrict__ att,
    float* __restrict__ h0, char* __restrict__ pack,
    float* __restrict__ a_self, float* __restrict__ a_neigh, int N, char* smem) {
    unsigned short* As = (unsigned short*)smem;
    float* sredA = (float*)(smem + 64 * ALD * 2);
    float* nredA = sredA + 128;
    int tid = threadIdx.x;
    int m0 = blockIdx.x * 64;
    // stage A: 64 rows x 128 k, f32 -> bf16 inline (32 float4-chunks/row)
    for (int i = tid; i < 2048; i += 256) {
        int row = i >> 5, ch = i & 31;
        int node = m0 + row;
        float4 f;
        if (node < N) f = *(const float4*)&feat[(size_t)node * 128 + ch * 4];
        else          f = make_float4(0.f, 0.f, 0.f, 0.f);
        unsigned p0 = (unsigned)f2bf(f.x) | ((unsigned)f2bf(f.y) << 16);
        unsigned p1 = (unsigned)f2bf(f.z) | ((unsigned)f2bf(f.w) << 16);
        *(uint2*)&As[row * ALD + ch * 4] = make_uint2(p0, p1);
    }
    __syncthreads();
    int w = tid >> 6, lane = tid & 63;
    int lm = lane & 15, q = lane >> 4;
    f32x4 acc[4][4];  // [row-tile][col-tile]
    #pragma unroll
    for (int rt = 0; rt < 4; ++rt)
        #pragma unroll
        for (int ct = 0; ct < 4; ++ct)
            #pragma unroll
            for (int r = 0; r < 4; ++r) acc[rt][ct][r] = 0.f;
    #pragma unroll
    for (int ks = 0; ks < 4; ++ks) {
        short8 a[4], b[4];
        #pragma unroll
        for (int rt = 0; rt < 4; ++rt)
            a[rt] = *(const short8*)&As[(rt * 16 + lm) * ALD + ks * 32 + q * 8];
        #pragma unroll
        for (int ct = 0; ct < 4; ++ct)
            b[ct] = *(const short8*)&Bt[(size_t)(w * 64 + ct * 16 + lm) * 128 + ks * 32 + q * 8];
        #pragma unroll
        for (int rt = 0; rt < 4; ++rt)
            #pragma unroll
            for (int ct = 0; ct < 4; ++ct)
                acc[rt][ct] = __builtin_amdgcn_mfma_f32_16x16x32_bf16(a[rt], b[ct], acc[rt][ct], 0, 0, 0);
    }
    // epilogue: bias + relu, store, att-dot partials
    float sacc[4][4];
    #pragma unroll
    for (int rt = 0; rt < 4; ++rt)
        #pragma unroll
        for (int r = 0; r < 4; ++r) sacc[rt][r] = 0.f;
    #pragma unroll
    for (int ct = 0; ct < 4; ++ct) {
        int col = w * 64 + ct * 16 + lm;  // 0..255, wave-uniform half
        float attc = att[col];
        float bias = (w < 2) ? b0[col] : b1[col - 128];
        int cp = col - 128;               // h1 dim for w>=2
        int pofs = ((cp >> 2) * 16 + (cp & 3) * 2);
        #pragma unroll
        for (int rt = 0; rt < 4; ++rt) {
            #pragma unroll
            for (int r = 0; r < 4; ++r) {
                float v = acc[rt][ct][r] + bias;
                v = fmaxf(v, 0.f);
                sacc[rt][r] += v * attc;
                int node = m0 + rt * 16 + q * 4 + r;
                if (node < N) {
                    if (w < 2) h0[(size_t)node * 128 + col] = v;
                    else       *(unsigned short*)(pack + (size_t)node * 512 + pofs) = f2bf(v);
                }
            }
        }
    }
    float* red = (w < 2) ? sredA : nredA;
    #pragma unroll
    for (int rt = 0; rt < 4; ++rt)
        #pragma unroll
        for (int r = 0; r < 4; ++r) {
            float s = sacc[rt][r];
            s += __shfl_xor(s, 1, 64); s += __shfl_xor(s, 2, 64);
            s += __shfl_xor(s, 4, 64); s += __shfl_xor(s, 8, 64);
            if (lm == 0) red[(w & 1) * 64 + rt * 16 + q * 4 + r] = s;
        }
    __syncthreads();
    if (tid < 64) {
        int node = m0 + tid;
        if (node < N) {
            float s  = sredA[tid] + sredA[64 + tid];
            float nn = nredA[tid] + nredA[64 + tid];
            a_self[node]  = (s  >= 0.f) ? s  : 0.2f * s;
            a_neigh[node] = (nn >= 0.f) ? nn : 0.2f * nn;
        }
    }
}

// decoupled-lookback exclusive scan: 256 thr/block, 1024 elems/block (4/thread)
// bstate[b] = (flag<<32)|value; flag 1 = aggregate ready, 2 = inclusive prefix ready
static __device__ __forceinline__ void scan_body(
    const int* __restrict__ deg, int* __restrict__ rowptr,
    unsigned long long* __restrict__ bstate, int n, int nbs, char* smem) {
    int b = blockIdx.x;
    if (b >= nbs) return;
    int* wsum = (int*)smem;        // [4]
    int* bprefs = (int*)smem + 8;  // [1]
    int tid = threadIdx.x, lane = tid & 63, w = tid >> 6;
    int base = b * 1024 + tid * 4;
    int4 v = make_int4(0, 0, 0, 0);
    if (base + 3 < n) v = *(const int4*)&deg[base];
    else {
        if (base     < n) v.x = deg[base];
        if (base + 1 < n) v.y = deg[base + 1];
        if (base + 2 < n) v.z = deg[base + 2];
        if (base + 3 < n) v.w = deg[base + 3];
    }
    int s = v.x + v.y + v.z + v.w;
    int x = s;
    #pragma unroll
    for (int off = 1; off < 64; off <<= 1) {
        int y = __shfl_up(x, off, 64);
        if (lane >= off) x += y;
    }
    if (lane == 63) wsum[w] = x;
    __syncthreads();
    int wpref = 0;
    for (int t = 0; t < w; ++t) wpref += wsum[t];
    int btotal = wsum[0] + wsum[1] + wsum[2] + wsum[3];
    int excl = x - s + wpref;  // exclusive prefix within block of this thread's quad
    if (tid == 0) {
        unsigned long long pack =
            ((unsigned long long)(b == 0 ? 2u : 1u) << 32) | (unsigned)btotal;
        atomicExch(&bstate[b], pack);
        int pref = 0;
        if (b > 0) {
            int i = b - 1;
            while (i >= 0) {
                unsigned long long st = atomicAdd(&bstate[i], 0ULL);
                unsigned f = (unsigned)(st >> 32);
                if (f == 0) { __builtin_amdgcn_s_sleep(1); continue; }
                pref += (int)(st & 0xffffffffULL);
                if (f == 2) break;
                --i;
            }
            atomicExch(&bstate[b], (2ULL << 32) | (unsigned)(pref + btotal));
        }
        bprefs[0] = pref;
    }
    __syncthreads();
    int p = bprefs[0] + excl;
    if (base + 3 < n) {
        *(int4*)&rowptr[base] = make_int4(p, p + v.x, p + v.x + v.y, p + v.x + v.y + v.z);
    } else {
        if (base     < n) rowptr[base]     = p;
        if (base + 1 < n) rowptr[base + 1] = p + v.x;
        if (base + 2 < n) rowptr[base + 2] = p + v.x + v.y;
        if (base + 3 < n) rowptr[base + 3] = p + v.x + v.y + v.z;
    }
    if (b == nbs - 1 && tid == 0) rowptr[n] = bprefs[0] + btotal;
}

__global__ __launch_bounds__(256) void k_fused(
    const float* __restrict__ feat, const float* __restrict__ Wp,
    const unsigned short* __restrict__ Bt,
    const float* __restrict__ b0, const float* __restrict__ b1,
    const float* __restrict__ att, const float* __restrict__ Wg,
    float* __restrict__ h0, char* __restrict__ pack,
    float* __restrict__ gpart, float* __restrict__ fdotg,
    float* __restrict__ a_self, float* __restrict__ a_neigh,
    const int* __restrict__ deg, int* __restrict__ rowptr,
    unsigned long long* __restrict__ bstate, int nbs, int N) {
    __shared__ __align__(16) char smem[SMEM_BYTES];
    if (blockIdx.y == 0)
        zj_body(feat, Wp, Wg, pack, gpart, fdotg, N, smem);
    else if (blockIdx.y == 1)
        mfma_body(feat, Bt, b0, b1, att, h0, pack, a_self, a_neigh, N, smem);
    else
        scan_body(deg, rowptr, bstate, N, nbs, smem);
}

// ---------- K3: scatter final edge meta into CSR slot ----------
// meta.x = byte offset of col record (c*512), meta.y = a_neigh[c], meta.z = vals*fdotg[c]
__global__ void k_scatter_meta(const int* __restrict__ rows, const int* __restrict__ cols,
                               const float* __restrict__ vals,
                               const int* __restrict__ rowptr, const int* __restrict__ slot,
                               const float* __restrict__ a_neigh, const float* __restrict__ fdotg,
                               float4* __restrict__ meta, int E) {
    int e = blockIdx.x * blockDim.x + threadIdx.x;
    if (e < E) {
        int c = cols[e];
        int dst = rowptr[rows[e]] + slot[e];
        meta[dst] = make_float4(__builtin_bit_cast(float, c << 9),
                                a_neigh[c], vals[e] * fdotg[c], 0.f);
    }
}

// ---------- K4: per-row CSR aggregation ----------
// 2 rows per wave (32 lanes/row, 4 dims/lane), packed 512B col records,
// one 16B gather per edge per lane. Wave-uniform trip count avoids
// divergence between the two half-wave rows; clamped loads duplicate the
// row's own last edge (max-idempotent for zmax, es masked to 0 for acc).
__global__ __launch_bounds__(256) void k_aggregate(
    const float4* __restrict__ meta, const int* __restrict__ rowptr,
    const float* __restrict__ h0, const char* __restrict__ pack,
    const float* __restrict__ a_self, const float* __restrict__ gpart,
    const float* __restrict__ Wg,
    const float* __restrict__ scale0, const float* __restrict__ offset0,
    const float* __restrict__ scale1, const float* __restrict__ offset1,
    float* __restrict__ out, int N) {
    int wid = threadIdx.x >> 6;
    int lane = threadIdx.x & 63;
    int sub = lane >> 5;      // which row in the wave
    int l = lane & 31;        // lane within row-group, owns dims 4l..4l+3
    int r = blockIdx.x * 8 + wid * 2 + sub;
    int rr = (r < N) ? r : (N - 1);
    int jb = rowptr[rr], je = rowptr[rr + 1];
    int trips = (je - jb + 7) >> 3;
    int tother = __shfl_xor(trips, 32, 64);
    int tmax = (trips > tother) ? trips : tother;
    int jclamp = (je > 0) ? je - 1 : 0;
    float asr = a_self[rr];
    const char* packl = pack + l * 16;
    float4 acc = make_float4(0.f, 0.f, 0.f, 0.f);
    float2 zmax = make_float2(-__builtin_inff(), -__builtin_inff());
    float vfsum = 0.f;
    for (int t0 = 0; t0 < tmax; ++t0) {
        int j = jb + t0 * 8;
        int joff[8]; float esv[8];
        #pragma unroll
        for (int t = 0; t < 8; ++t) {
            int jj = j + t;
            bool a = jj < je;
            float4 mt = meta[a ? jj : jclamp];
            joff[t] = __builtin_bit_cast(int, mt.x);
            esv[t] = a ? (asr + mt.y) : 0.f;
            vfsum += a ? mt.z : 0.f;
        }
        uint4 v[8];
        #pragma unroll
        for (int t = 0; t < 8; ++t)
            v[t] = *(const uint4*)(packl + (size_t)(unsigned)joff[t]);
        #pragma unroll
        for (int t = 0; t < 8; ++t) {
            float e = esv[t];
            acc.x += e * bflo(v[t].x);
            acc.y += e * bfhi(v[t].x);
            acc.z += e * bflo(v[t].y);
            acc.w += e * bfhi(v[t].y);
            zmax.x = fmaxf(zmax.x, __builtin_bit_cast(float, v[t].z));
            zmax.y = fmaxf(zmax.y, __builtin_bit_cast(float, v[t].w));
        }
    }
    if (jb == je) { zmax.x = 0.f; zmax.y = 0.f; }  // empty segment: -inf -> 0
    float gs = zmax.x * Wg[128 + 2 * l] + zmax.y * Wg[129 + 2 * l];
    #pragma unroll
    for (int off = 16; off; off >>= 1) gs += __shfl_xor(gs, off, 64);
    float gate = gpart[rr] + gs + vfsum;  // all-f32 gate path (sign matters)
    float4 ag = make_float4(acc.x * gate, acc.y * gate, acc.z * gate, acc.w * gate);
    // BN on h0 row
    float4 x0 = ((const float4*)(h0 + (size_t)rr * 128))[l];
    float m0s = x0.x + x0.y + x0.z + x0.w;
    #pragma unroll
    for (int off = 16; off; off >>= 1) m0s += __shfl_xor(m0s, off, 64);
    float m0 = m0s * (1.f / 128.f);
    float4 d0 = make_float4(x0.x - m0, x0.y - m0, x0.z - m0, x0.w - m0);
    float v0s = d0.x * d0.x + d0.y * d0.y + d0.z * d0.z + d0.w * d0.w;
    #pragma unroll
    for (int off = 16; off; off >>= 1) v0s += __shfl_xor(v0s, off, 64);
    float inv0 = rsqrtf(v0s * (1.f / 128.f) + 1e-9f);
    // BN on gated aggregation
    float m1s = ag.x + ag.y + ag.z + ag.w;
    #pragma unroll
    for (int off = 16; off; off >>= 1) m1s += __shfl_xor(m1s, off, 64);
    float m1 = m1s * (1.f / 128.f);
    float4 d1 = make_float4(ag.x - m1, ag.y - m1, ag.z - m1, ag.w - m1);
    float v1s = d1.x * d1.x + d1.y * d1.y + d1.z * d1.z + d1.w * d1.w;
    #pragma unroll
    for (int off = 16; off; off >>= 1) v1s += __shfl_xor(v1s, off, 64);
    float inv1 = rsqrtf(v1s * (1.f / 128.f) + 1e-9f);
    if (r >= N) return;
    float4 sc0 = ((const float4*)scale0)[l], of0 = ((const float4*)offset0)[l];
    float4 sc1 = ((const float4*)scale1)[l], of1 = ((const float4*)offset1)[l];
    float4 o;
    o.x = d0.x * sc0.x * inv0 + of0.x + d1.x * sc1.x * inv1 + of1.x;
    o.y = d0.y * sc0.y * inv0 + of0.y + d1.y * sc1.y * inv1 + of1.y;
    o.z = d0.z * sc0.z * inv0 + of0.z + d1.z * sc1.z * inv1 + of1.z;
    o.w = d0.w * sc0.w * inv0 + of0.w + d1.w * sc1.w * inv1 + of1.w;
    ((float4*)(out + (size_t)r * 128))[l] = o;
}

extern "C" void kernel_launch(void* const* d_in, const int* in_sizes, int n_in,
                              void* d_out, int out_size, void* d_ws, size_t ws_size,
                              hipStream_t stream) {
    const int*   rows   = (const int*)d_in[0];
    const int*   cols   = (const int*)d_in[1];
    const float* vals   = (const float*)d_in[2];
    const float* feat   = (const float*)d_in[3];
    const float* W0     = (const float*)d_in[4];
    const float* b0     = (const float*)d_in[5];
    const float* W1     = (const float*)d_in[6];
    const float* b1     = (const float*)d_in[7];
    const float* att    = (const float*)d_in[8];
    const float* Wp     = (const float*)d_in[9];
    const float* Wg     = (const float*)d_in[10];
    const float* offset0 = (const float*)d_in[11];
    const float* scale0  = (const float*)d_in[12];
    const float* offset1 = (const float*)d_in[13];
    const float* scale1  = (const float*)d_in[14];
    float* out = (float*)d_out;

    const int E = in_sizes[0];
    const int N = in_sizes[3] / DIN;
    const int Npad = (N + 63) & ~63;

    char* ws = (char*)d_ws;
    float* h0          = (float*)ws;          ws += (size_t)N * 128 * sizeof(float);
    char* pack         = ws;                  ws += (size_t)N * 512;  // replaces hb (N*256B) + zj (N*256B)
    unsigned short* Bt = (unsigned short*)ws; ws += (size_t)256 * 128 * sizeof(unsigned short);
    float* a_self  = (float*)ws; ws += (size_t)N * sizeof(float);
    float* a_neigh = (float*)ws; ws += (size_t)N * sizeof(float);
    float* gpart   = (float*)ws; ws += (size_t)N * sizeof(float);
    float* fdotg   = (float*)ws; ws += (size_t)N * sizeof(float);
    ws = (char*)(((size_t)ws + 7) & ~(size_t)7);
    unsigned long long* bstate = (unsigned long long*)ws; ws += 64 * sizeof(unsigned long long);
    int* deg      = (int*)ws; ws += (size_t)(N + 1) * sizeof(int);
    int* rowptr   = (int*)ws; ws += (size_t)(N + 1) * sizeof(int);
    int* slot     = (int*)ws; ws += (size_t)E * sizeof(int);
    ws = (char*)(((size_t)ws + 15) & ~(size_t)15);
    float4* meta  = (float4*)ws; ws += (size_t)E * sizeof(float4);

    // zero bstate (flags) + deg in one memset (contiguous in ws)
    hipMemsetAsync(bstate, 0, 64 * sizeof(unsigned long long) + (size_t)(N + 1) * sizeof(int), stream);

    int nDeg = (E + 255) / 256;
    k_pre<<<nDeg + 128, 256, 0, stream>>>(rows, deg, slot, E, nDeg, W0, W1, Bt);

    int nbs = (N + 1023) >> 10;  // 49 for N=50000 (scan role blocks)
    dim3 gg(Npad / 64, 3);       // y=0: zj (x<ceil(N/128)), y=1: mfma, y=2: scan (x<nbs)
    k_fused<<<gg, 256, 0, stream>>>(feat, Wp, Bt, b0, b1, att, Wg,
                                    h0, pack, gpart, fdotg, a_self, a_neigh,
                                    deg, rowptr, bstate, nbs, N);

    k_scatter_meta<<<nDeg, 256, 0, stream>>>(rows, cols, vals, rowptr, slot,
                                             a_neigh, fdotg, meta, E);

    int nb8 = (N + 7) / 8;
    k_aggregate<<<nb8, 256, 0, stream>>>(meta, rowptr, h0, pack,
                                         a_self, gpart, Wg,
                                         scale0, offset0, scale1, offset1, out, N);
}